// Round 1
// baseline (183.457 us; speedup 1.0000x reference)
//
#include <hip/hip_runtime.h>

#define NE 8
#define HD 128
#define NPTS 65536
#define TM 128

typedef __bf16 bf16x8 __attribute__((ext_vector_type(8)));
typedef float f32x4 __attribute__((ext_vector_type(4)));

__device__ __forceinline__ unsigned short f2bf(float f) {
    unsigned int u = __float_as_uint(f);
    u += 0x7FFFu + ((u >> 16) & 1u);   // round-to-nearest-even
    return (unsigned short)(u >> 16);
}
__device__ __forceinline__ float bf2f_lo(unsigned int u) { return __uint_as_float(u << 16); }
__device__ __forceinline__ float bf2f_hi(unsigned int u) { return __uint_as_float(u & 0xFFFF0000u); }

// XOR swizzle: spreads 8 consecutive rows across 8 distinct 16B slots -> conflict-free-ish ds_read_b128
__device__ __forceinline__ unsigned int swz(int row, int byte_in_row) {
    return (unsigned int)((row * 256 + byte_in_row) ^ ((row & 7) << 4));
}

// GEMM: D[r][c] = relu(sum_k A[r][k] * W[c][k] + bias[c]); A,W,D bf16 in LDS (swizzled), TM=128, H=128.
// 4 waves in 2x2 grid, each wave 64 rows x 64 cols (Mf=Nf=4 tiles of 16x16, K in 4 steps of 32).
__device__ __forceinline__ void gemm_relu(const unsigned short* Asrc, const unsigned short* Bsrc,
                                          unsigned short* Dst, const float* __restrict__ bias,
                                          int w, int lane) {
    const char* Ab = (const char*)Asrc;
    const char* Bb = (const char*)Bsrc;
    char* Db = (char*)Dst;
    const int wrow = (w >> 1) * 64;
    const int wcol = (w & 1) * 64;
    const int lr = lane & 15;
    const int lg = lane >> 4;

    f32x4 acc[4][4];
#pragma unroll
    for (int m = 0; m < 4; ++m)
#pragma unroll
        for (int n = 0; n < 4; ++n)
            acc[m][n] = (f32x4){0.f, 0.f, 0.f, 0.f};

#pragma unroll
    for (int kb = 0; kb < 4; ++kb) {
        const int kof = kb * 64 + lg * 16;  // byte offset of this lane's 8 contiguous k (k = kb*32 + lg*8)
        bf16x8 a[4], b[4];
#pragma unroll
        for (int m = 0; m < 4; ++m) {
            int r = wrow + m * 16 + lr;
            a[m] = *(const bf16x8*)(Ab + swz(r, kof));
        }
#pragma unroll
        for (int n = 0; n < 4; ++n) {
            int c = wcol + n * 16 + lr;
            b[n] = *(const bf16x8*)(Bb + swz(c, kof));
        }
#pragma unroll
        for (int m = 0; m < 4; ++m)
#pragma unroll
            for (int n = 0; n < 4; ++n)
                acc[m][n] = __builtin_amdgcn_mfma_f32_16x16x32_bf16(a[m], b[n], acc[m][n], 0, 0, 0);
    }

    // D layout (m89): col = lane&15, row = (lane>>4)*4 + j
#pragma unroll
    for (int n = 0; n < 4; ++n) {
        int c = wcol + n * 16 + lr;
        float bs = bias[c];
#pragma unroll
        for (int m = 0; m < 4; ++m) {
            int rb = wrow + m * 16 + lg * 4;
#pragma unroll
            for (int j = 0; j < 4; ++j) {
                float v = fmaxf(acc[m][n][j] + bs, 0.0f);
                *(unsigned short*)(Db + swz(rb + j, c * 2)) = f2bf(v);
            }
        }
    }
}

__global__ __launch_bounds__(256, 1) void moe_mlp_kernel(
    const float* __restrict__ coords,
    const float* __restrict__ W0, const float* __restrict__ b0,
    const float* __restrict__ W1, const float* __restrict__ b1,
    const float* __restrict__ W2, const float* __restrict__ b2,
    const float* __restrict__ Wo, const float* __restrict__ bo,
    float* __restrict__ out) {
    __shared__ unsigned short hA[TM * HD];  // 32 KB activations ping
    __shared__ unsigned short hB[TM * HD];  // 32 KB activations pong
    __shared__ unsigned short Wb[HD * HD];  // 32 KB staged layer weights (bf16, swizzled)
    __shared__ float xs[TM * 3];
    __shared__ float wos[HD];
    __shared__ float best[TM];

    const int tid = threadIdx.x;
    const int lane = tid & 63;
    const int w = tid >> 6;
    const int row0 = blockIdx.x * TM;

    for (int i = tid; i < TM * 3; i += 256) xs[i] = coords[row0 * 3 + i];
    if (tid < TM) best[tid] = -3.0e38f;
    __syncthreads();

    for (int e = 0; e < NE; ++e) {
        // ---- stage W1_e -> Wb (fp32 -> bf16, swizzled); coalesced float4 reads ----
        {
            const float* Wg = W1 + e * HD * HD;
            char* base = (char*)Wb;
#pragma unroll
            for (int i = 0; i < 16; ++i) {
                int idx = i * 1024 + tid * 4;
                float4 v = *(const float4*)(Wg + idx);
                int n = idx >> 7;
                int k = idx & 127;
                uint2 p;
                p.x = (unsigned int)f2bf(v.x) | ((unsigned int)f2bf(v.y) << 16);
                p.y = (unsigned int)f2bf(v.z) | ((unsigned int)f2bf(v.w) << 16);
                *(uint2*)(base + swz(n, k * 2)) = p;
            }
        }
        // ---- h1 = relu(X * W0_e^T + b0_e) -> hA; thread owns col-pair (2p,2p+1) x 32 rows ----
        {
            const int p = tid & 63;
            const int q = tid >> 6;
            const int c = 2 * p;
            const float* W0e = W0 + e * HD * 3;
            const float wa0 = W0e[c * 3 + 0], wa1 = W0e[c * 3 + 1], wa2 = W0e[c * 3 + 2];
            const float wb0 = W0e[c * 3 + 3], wb1 = W0e[c * 3 + 4], wb2 = W0e[c * 3 + 5];
            const float ba = b0[e * HD + c], bb = b0[e * HD + c + 1];
            char* base = (char*)hA;
#pragma unroll
            for (int rr = 0; rr < 32; ++rr) {
                int r = q * 32 + rr;
                float x0 = xs[r * 3 + 0], x1 = xs[r * 3 + 1], x2 = xs[r * 3 + 2];
                float va = fmaxf(fmaf(x0, wa0, fmaf(x1, wa1, fmaf(x2, wa2, ba))), 0.f);
                float vb = fmaxf(fmaf(x0, wb0, fmaf(x1, wb1, fmaf(x2, wb2, bb))), 0.f);
                unsigned int pk = (unsigned int)f2bf(va) | ((unsigned int)f2bf(vb) << 16);
                *(unsigned int*)(base + swz(r, c * 2)) = pk;
            }
        }
        __syncthreads();

        // ---- h2 = relu(h1 * W1^T + b1) -> hB ----
        gemm_relu(hA, Wb, hB, b1 + e * HD, w, lane);
        __syncthreads();

        // ---- stage W2_e -> Wb; also stage Wo_e ----
        {
            const float* Wg = W2 + e * HD * HD;
            char* base = (char*)Wb;
#pragma unroll
            for (int i = 0; i < 16; ++i) {
                int idx = i * 1024 + tid * 4;
                float4 v = *(const float4*)(Wg + idx);
                int n = idx >> 7;
                int k = idx & 127;
                uint2 p;
                p.x = (unsigned int)f2bf(v.x) | ((unsigned int)f2bf(v.y) << 16);
                p.y = (unsigned int)f2bf(v.z) | ((unsigned int)f2bf(v.w) << 16);
                *(uint2*)(base + swz(n, k * 2)) = p;
            }
            if (tid < HD) wos[tid] = Wo[e * HD + tid];
        }
        __syncthreads();

        // ---- h3 = relu(h2 * W2^T + b2) -> hA ----
        gemm_relu(hB, Wb, hA, b2 + e * HD, w, lane);
        __syncthreads();

        // ---- out_e[r] = sum_k h3[r][k]*Wo[k] + bo; max into best. 2 threads per row ----
        {
            const int r = tid >> 1;
            const int hf = tid & 1;
            const char* base = (const char*)hA;
            float s = 0.f;
#pragma unroll
            for (int j = 0; j < 8; ++j) {
                int k = hf * 64 + j * 8;
                uint4 qv = *(const uint4*)(base + swz(r, k * 2));
                s += bf2f_lo(qv.x) * wos[k + 0] + bf2f_hi(qv.x) * wos[k + 1]
                   + bf2f_lo(qv.y) * wos[k + 2] + bf2f_hi(qv.y) * wos[k + 3]
                   + bf2f_lo(qv.z) * wos[k + 4] + bf2f_hi(qv.z) * wos[k + 5]
                   + bf2f_lo(qv.w) * wos[k + 6] + bf2f_hi(qv.w) * wos[k + 7];
            }
            s += __shfl_xor(s, 1);
            if (hf == 0) {
                float v = s + bo[e];
                best[r] = fmaxf(best[r], v);
            }
        }
        __syncthreads();
    }

    if (tid < TM) out[row0 + tid] = best[tid];
}

extern "C" void kernel_launch(void* const* d_in, const int* in_sizes, int n_in,
                              void* d_out, int out_size, void* d_ws, size_t ws_size,
                              hipStream_t stream) {
    const float* coords = (const float*)d_in[0];
    const float* W0 = (const float*)d_in[1];
    const float* b0 = (const float*)d_in[2];
    const float* W1 = (const float*)d_in[3];
    const float* b1 = (const float*)d_in[4];
    const float* W2 = (const float*)d_in[5];
    const float* b2 = (const float*)d_in[6];
    const float* Wo = (const float*)d_in[7];
    const float* bo = (const float*)d_in[8];
    float* out = (float*)d_out;

    dim3 grid(NPTS / TM);   // 512 blocks
    dim3 block(256);        // 4 waves
    moe_mlp_kernel<<<grid, block, 0, stream>>>(coords, W0, b0, W1, b1, W2, b2, Wo, bo, out);
}

// Round 2
// 90.953 us; speedup vs baseline: 2.0171x; 2.0171x over previous
//
#include <hip/hip_runtime.h>

#define NE 8
#define HD 128
#define NPTS 65536
#define TM 64   // points per block

typedef __bf16 bf16x8 __attribute__((ext_vector_type(8)));
typedef float f32x4 __attribute__((ext_vector_type(4)));

__device__ __forceinline__ unsigned int f2bf(float f) {
    unsigned int u = __float_as_uint(f);
    u += 0x7FFFu + ((u >> 16) & 1u);   // round-to-nearest-even
    return u >> 16;
}
__device__ __forceinline__ float bf2f_lo(unsigned int u) { return __uint_as_float(u << 16); }
__device__ __forceinline__ float bf2f_hi(unsigned int u) { return __uint_as_float(u & 0xFFFF0000u); }

// XOR swizzle on 256B rows: spreads 8 consecutive rows across 8 distinct 16B slots
__device__ __forceinline__ unsigned int swz(int row, int byte_in_row) {
    return (unsigned int)((row * 256 + byte_in_row) ^ ((row & 7) << 4));
}

// GEMM with A (weights, bf16) read straight from global, B (activations) from LDS.
// Computes D[r][c] = relu( sum_k B[r][k] * A[c][k] + bias[c] ) for r in [0,64), c in [0,128).
// Wave w owns c-range [w*32, w*32+32) x all 64 points. mfma(a=W-rows, b=h-rows):
// lane holds point r = tile + (lane&15), hidden c = tile + (lane>>4)*4 + j  -> packed b64 writes.
template<int NKB, int BSTR, bool BSWZ>
__device__ __forceinline__ void gemm_gA(const unsigned short* __restrict__ Ag,
                                        const char* Bb, char* Db,
                                        const float* __restrict__ bias,
                                        int w, int lane) {
    const int lr = lane & 15;
    const int lg = lane >> 4;
    const int tc = w * 32;

    f32x4 acc[2][4];
#pragma unroll
    for (int ca = 0; ca < 2; ++ca)
#pragma unroll
        for (int nb = 0; nb < 4; ++nb)
            acc[ca][nb] = (f32x4){0.f, 0.f, 0.f, 0.f};

#pragma unroll
    for (int kb = 0; kb < NKB; ++kb) {
        bf16x8 a[2], b[4];
#pragma unroll
        for (int ca = 0; ca < 2; ++ca) {
            int c = tc + ca * 16 + lr;
            a[ca] = *(const bf16x8*)(Ag + c * (NKB * 32) + kb * 32 + lg * 8);
        }
#pragma unroll
        for (int nb = 0; nb < 4; ++nb) {
            int r = nb * 16 + lr;
            int byte = kb * 64 + lg * 16;
            const char* p = BSWZ ? (Bb + swz(r, byte)) : (Bb + r * BSTR + byte);
            b[nb] = *(const bf16x8*)p;
        }
#pragma unroll
        for (int ca = 0; ca < 2; ++ca)
#pragma unroll
            for (int nb = 0; nb < 4; ++nb)
                acc[ca][nb] = __builtin_amdgcn_mfma_f32_16x16x32_bf16(a[ca], b[nb], acc[ca][nb], 0, 0, 0);
    }

    // Epilogue: lane writes 4 consecutive hidden c for its point r -> one b64 per acc tile
#pragma unroll
    for (int ca = 0; ca < 2; ++ca) {
        int c0 = tc + ca * 16 + lg * 4;
        float4 bs = *(const float4*)(bias + c0);
#pragma unroll
        for (int nb = 0; nb < 4; ++nb) {
            int r = nb * 16 + lr;
            f32x4 v = acc[ca][nb];
            float v0 = fmaxf(v[0] + bs.x, 0.f);
            float v1 = fmaxf(v[1] + bs.y, 0.f);
            float v2 = fmaxf(v[2] + bs.z, 0.f);
            float v3 = fmaxf(v[3] + bs.w, 0.f);
            uint2 p;
            p.x = f2bf(v0) | (f2bf(v1) << 16);
            p.y = f2bf(v2) | (f2bf(v3) << 16);
            *(uint2*)(Db + swz(r, c0 * 2)) = p;
        }
    }
}

// Prep: fp32 -> bf16 weights into workspace. W0 padded K:3->32 with zeros.
__global__ void prep_kernel(const float* __restrict__ W0,
                            const float* __restrict__ W1,
                            const float* __restrict__ W2,
                            unsigned int* __restrict__ W1b,
                            unsigned int* __restrict__ W2b,
                            unsigned int* __restrict__ W0p) {
    int i = blockIdx.x * 256 + threadIdx.x;  // 0..65535
    float2 v = *(const float2*)(W1 + 2 * i);
    W1b[i] = f2bf(v.x) | (f2bf(v.y) << 16);
    float2 u = *(const float2*)(W2 + 2 * i);
    W2b[i] = f2bf(u.x) | (f2bf(u.y) << 16);
    if (i < NE * HD * 16) {   // 16384 pairs of the padded [E*128][32] W0
        int row = i >> 4;
        int kk = (i & 15) * 2;
        float a = (kk < 3) ? W0[row * 3 + kk] : 0.f;
        float b = (kk + 1 < 3) ? W0[row * 3 + kk + 1] : 0.f;
        W0p[i] = f2bf(a) | (f2bf(b) << 16);
    }
}

__global__ __launch_bounds__(256, 4) void moe_main(
    const float* __restrict__ coords,
    const float* __restrict__ b0, const float* __restrict__ b1,
    const float* __restrict__ b2,
    const float* __restrict__ Wo, const float* __restrict__ bo,
    const unsigned short* __restrict__ W0p,
    const unsigned short* __restrict__ W1b,
    const unsigned short* __restrict__ W2b,
    float* __restrict__ out) {
    __shared__ __align__(16) unsigned short hA[TM * HD];   // 16 KB, swizzled 256B rows
    __shared__ __align__(16) unsigned short hB[TM * HD];   // 16 KB
    __shared__ __align__(16) unsigned short Xp[TM * 40];   // 5 KB, 80B rows (K padded to 32)
    __shared__ __align__(16) float wos[HD];

    const int tid = threadIdx.x;
    const int lane = tid & 63;
    const int w = tid >> 6;
    const int row0 = blockIdx.x * TM;

    for (int i = tid; i < TM * 40; i += 256) Xp[i] = 0;
    __syncthreads();
    if (tid < TM * 3) {
        int r = tid / 3, k = tid % 3;
        Xp[r * 40 + k] = (unsigned short)f2bf(coords[row0 * 3 + tid]);
    }
    __syncthreads();

    float bmax = -3.0e38f;
    const int dr = tid >> 2, dq = tid & 3;

    for (int e = 0; e < NE; ++e) {
        if (tid < HD) wos[tid] = Wo[e * HD + tid];
        // layer0: h1 = relu(X*W0^T + b0), K padded to 32
        gemm_gA<1, 80, false>(W0p + e * HD * 32, (const char*)Xp, (char*)hA, b0 + e * HD, w, lane);
        __syncthreads();
        // layer1
        gemm_gA<4, 0, true>(W1b + e * HD * HD, (const char*)hA, (char*)hB, b1 + e * HD, w, lane);
        __syncthreads();
        // layer2
        gemm_gA<4, 0, true>(W2b + e * HD * HD, (const char*)hB, (char*)hA, b2 + e * HD, w, lane);
        __syncthreads();
        // output dot + running max (4 threads per point)
        float s = 0.f;
        const char* base = (const char*)hA;
#pragma unroll
        for (int j = 0; j < 4; ++j) {
            uint4 qv = *(const uint4*)(base + swz(dr, dq * 64 + j * 16));
            int k0 = dq * 32 + j * 8;
            float4 wa = *(const float4*)(wos + k0);
            float4 wb = *(const float4*)(wos + k0 + 4);
            s += bf2f_lo(qv.x) * wa.x + bf2f_hi(qv.x) * wa.y
               + bf2f_lo(qv.y) * wa.z + bf2f_hi(qv.y) * wa.w
               + bf2f_lo(qv.z) * wb.x + bf2f_hi(qv.z) * wb.y
               + bf2f_lo(qv.w) * wb.z + bf2f_hi(qv.w) * wb.w;
        }
        s += __shfl_xor(s, 1);
        s += __shfl_xor(s, 2);
        bmax = fmaxf(bmax, s + bo[e]);
        __syncthreads();   // protect hA before next expert's layer0 write
    }
    if (dq == 0) out[row0 + dr] = bmax;
}

extern "C" void kernel_launch(void* const* d_in, const int* in_sizes, int n_in,
                              void* d_out, int out_size, void* d_ws, size_t ws_size,
                              hipStream_t stream) {
    const float* coords = (const float*)d_in[0];
    const float* W0 = (const float*)d_in[1];
    const float* b0 = (const float*)d_in[2];
    const float* W1 = (const float*)d_in[3];
    const float* b1 = (const float*)d_in[4];
    const float* W2 = (const float*)d_in[5];
    const float* b2 = (const float*)d_in[6];
    const float* Wo = (const float*)d_in[7];
    const float* bo = (const float*)d_in[8];
    float* out = (float*)d_out;

    char* ws = (char*)d_ws;
    unsigned short* W1b = (unsigned short*)(ws);            // 8*128*128 bf16 = 256 KB
    unsigned short* W2b = (unsigned short*)(ws + 262144);   // 256 KB
    unsigned short* W0p = (unsigned short*)(ws + 524288);   // 8*128*32 bf16 = 64 KB

    prep_kernel<<<dim3(256), dim3(256), 0, stream>>>(
        W0, W1, W2, (unsigned int*)W1b, (unsigned int*)W2b, (unsigned int*)W0p);

    moe_main<<<dim3(NPTS / TM), dim3(256), 0, stream>>>(
        coords, b0, b1, b2, Wo, bo, W0p, W1b, W2b, out);
}

// Round 3
// 78.354 us; speedup vs baseline: 2.3414x; 1.1608x over previous
//
#include <hip/hip_runtime.h>

#define NE 8
#define HD 128
#define NPTS 65536
#define TM 64   // points per block

typedef __bf16 bf16x8 __attribute__((ext_vector_type(8)));
typedef __bf16 bf16x4 __attribute__((ext_vector_type(4)));
typedef float f32x4 __attribute__((ext_vector_type(4)));

__device__ __forceinline__ unsigned int f2bf(float f) {
    unsigned int u = __float_as_uint(f);
    u += 0x7FFFu + ((u >> 16) & 1u);   // RNE
    return u >> 16;
}

// XOR swizzle on 256B rows: spreads 8 consecutive rows across 8 distinct 16B slots
__device__ __forceinline__ unsigned int swz(int row, int byte_in_row) {
    return (unsigned int)((row * 256 + byte_in_row) ^ ((row & 7) << 4));
}

// LDS-only barrier: drains ds ops but leaves global (vmcnt) loads in flight.
// All inter-wave data deps in this kernel are through LDS, so this is sufficient.
__device__ __forceinline__ void bar_lds() {
    asm volatile("s_waitcnt lgkmcnt(0)\ns_barrier" ::: "memory");
}

// ---- A-fragment loaders (weights, bf16, from global/L2) ----
template<int KB0, int KB1>
__device__ __forceinline__ void loadA128(const unsigned short* __restrict__ Ag,
                                         bf16x8 (&a)[2][4], int tc, int lr, int lg) {
#pragma unroll
    for (int ca = 0; ca < 2; ++ca)
#pragma unroll
        for (int kb = KB0; kb < KB1; ++kb)
            a[ca][kb] = *(const bf16x8*)(Ag + (tc + ca * 16 + lr) * HD + kb * 32 + lg * 8);
}

__device__ __forceinline__ void loadA32(const unsigned short* __restrict__ Ag,
                                        bf16x8 (&a)[2][1], int tc, int lr, int lg) {
#pragma unroll
    for (int ca = 0; ca < 2; ++ca)
        a[ca][0] = *(const bf16x8*)(Ag + (tc + ca * 16 + lr) * 32 + lg * 8);
}

// ---- MFMA core: acc[ca][nb] += B(points) x A(weights) over NKB k-blocks ----
template<int NKB, bool BSWZ, int BSTR>
__device__ __forceinline__ void gemm_core(const bf16x8 (&a)[2][NKB], const char* Bb,
                                          f32x4 (&acc)[2][4], int lr, int lg) {
#pragma unroll
    for (int kb = 0; kb < NKB; ++kb) {
        bf16x8 b[4];
#pragma unroll
        for (int nb = 0; nb < 4; ++nb) {
            int r = nb * 16 + lr;
            int byte = kb * 64 + lg * 16;
            const char* p = BSWZ ? (Bb + swz(r, byte)) : (Bb + r * BSTR + byte);
            b[nb] = *(const bf16x8*)p;
        }
#pragma unroll
        for (int ca = 0; ca < 2; ++ca)
#pragma unroll
            for (int nb = 0; nb < 4; ++nb)
                acc[ca][nb] = __builtin_amdgcn_mfma_f32_16x16x32_bf16(a[ca][kb], b[nb], acc[ca][nb], 0, 0, 0);
    }
}

// ---- bias + relu + bf16-pack + swizzled LDS store ----
__device__ __forceinline__ void epi_store(const f32x4 (&acc)[2][4], char* Db,
                                          const float* __restrict__ bias,
                                          int tc, int lr, int lg) {
#pragma unroll
    for (int ca = 0; ca < 2; ++ca) {
        int c0 = tc + ca * 16 + lg * 4;
        float4 bs = *(const float4*)(bias + c0);
#pragma unroll
        for (int nb = 0; nb < 4; ++nb) {
            int r = nb * 16 + lr;
            bf16x4 pk;
            pk[0] = (__bf16)fmaxf(acc[ca][nb][0] + bs.x, 0.f);
            pk[1] = (__bf16)fmaxf(acc[ca][nb][1] + bs.y, 0.f);
            pk[2] = (__bf16)fmaxf(acc[ca][nb][2] + bs.z, 0.f);
            pk[3] = (__bf16)fmaxf(acc[ca][nb][3] + bs.w, 0.f);
            *(bf16x4*)(Db + swz(r, c0 * 2)) = pk;
        }
    }
}

// Prep: fp32 -> bf16 weights into workspace. W0 padded K:3->32 with zeros.
__global__ void prep_kernel(const float* __restrict__ W0,
                            const float* __restrict__ W1,
                            const float* __restrict__ W2,
                            unsigned int* __restrict__ W1b,
                            unsigned int* __restrict__ W2b,
                            unsigned int* __restrict__ W0p) {
    int i = blockIdx.x * 256 + threadIdx.x;  // 0..65535
    float2 v = *(const float2*)(W1 + 2 * i);
    W1b[i] = f2bf(v.x) | (f2bf(v.y) << 16);
    float2 u = *(const float2*)(W2 + 2 * i);
    W2b[i] = f2bf(u.x) | (f2bf(u.y) << 16);
    if (i < NE * HD * 16) {
        int row = i >> 4;
        int kk = (i & 15) * 2;
        float a = (kk < 3) ? W0[row * 3 + kk] : 0.f;
        float b = (kk + 1 < 3) ? W0[row * 3 + kk + 1] : 0.f;
        W0p[i] = f2bf(a) | (f2bf(b) << 16);
    }
}

__global__ __launch_bounds__(256, 4) void moe_main(
    const float* __restrict__ coords,
    const float* __restrict__ b0, const float* __restrict__ b1,
    const float* __restrict__ b2,
    const float* __restrict__ Wo, const float* __restrict__ bo,
    const unsigned short* __restrict__ W0p,
    const unsigned short* __restrict__ W1b,
    const unsigned short* __restrict__ W2b,
    float* __restrict__ out) {
    __shared__ __align__(16) unsigned short hA[TM * HD];   // 16 KB, swizzled 256B rows
    __shared__ __align__(16) unsigned short hB[TM * HD];   // 16 KB
    __shared__ __align__(16) unsigned short Xp[TM * 32];   // 4 KB, 64B rows (K padded to 32)
    __shared__ __align__(16) float part[256];              // per-wave dot partials [w][point]

    const int tid = threadIdx.x;
    const int lane = tid & 63;
    const int w = tid >> 6;
    const int lr = lane & 15;
    const int lg = lane >> 4;
    const int tc = w * 32;
    const int row0 = blockIdx.x * TM;

    for (int i = tid; i < TM * 32; i += 256) Xp[i] = 0;
    __syncthreads();
    if (tid < TM * 3) {
        int r = tid / 3, k = tid % 3;
        Xp[r * 32 + k] = (unsigned short)f2bf(coords[row0 * 3 + tid]);
    }
    __syncthreads();

    float bmax = -3.0e38f;
    bf16x8 a0[2][1], a1[2][4], a2[2][4];
    loadA32(W0p, a0, tc, lr, lg);   // expert 0 layer-0 weights

    for (int e = 0; e < NE; ++e) {
        const unsigned short* W1e = W1b + e * HD * HD;
        const unsigned short* W2e = W2b + e * HD * HD;

        // ---- layer 0: h1 = relu(X*W0^T + b0) -> hA ----
        loadA128<0, 2>(W1e, a1, tc, lr, lg);   // prefetch half of L1 weights
        f32x4 acc[2][4];
#pragma unroll
        for (int ca = 0; ca < 2; ++ca)
#pragma unroll
            for (int nb = 0; nb < 4; ++nb) acc[ca][nb] = (f32x4){0.f, 0.f, 0.f, 0.f};
        gemm_core<1, false, 64>(a0, (const char*)Xp, acc, lr, lg);
        epi_store(acc, (char*)hA, b0 + e * HD, tc, lr, lg);
        bar_lds();

        // ---- layer 1: h2 = relu(h1*W1^T + b1) -> hB ----
        loadA128<2, 4>(W1e, a1, tc, lr, lg);
        loadA128<0, 2>(W2e, a2, tc, lr, lg);   // prefetch half of L2 weights
#pragma unroll
        for (int ca = 0; ca < 2; ++ca)
#pragma unroll
            for (int nb = 0; nb < 4; ++nb) acc[ca][nb] = (f32x4){0.f, 0.f, 0.f, 0.f};
        gemm_core<4, true, 0>(a1, (const char*)hA, acc, lr, lg);
        epi_store(acc, (char*)hB, b1 + e * HD, tc, lr, lg);
        bar_lds();

        // ---- layer 2 + fused output dot ----
        loadA128<2, 4>(W2e, a2, tc, lr, lg);
        loadA32(W0p + (e < 7 ? e + 1 : 7) * HD * 32, a0, tc, lr, lg);  // prefetch next expert L0
#pragma unroll
        for (int ca = 0; ca < 2; ++ca)
#pragma unroll
            for (int nb = 0; nb < 4; ++nb) acc[ca][nb] = (f32x4){0.f, 0.f, 0.f, 0.f};
        gemm_core<4, true, 0>(a2, (const char*)hB, acc, lr, lg);

        {
            const float* b2e = b2 + e * HD;
            const float* Woe = Wo + e * HD;
            float s[4] = {0.f, 0.f, 0.f, 0.f};
#pragma unroll
            for (int ca = 0; ca < 2; ++ca) {
                int c0 = tc + ca * 16 + lg * 4;
                float4 bs = *(const float4*)(b2e + c0);
                float4 wo = *(const float4*)(Woe + c0);
#pragma unroll
                for (int nb = 0; nb < 4; ++nb) {
                    float v0 = fmaxf(acc[ca][nb][0] + bs.x, 0.f);
                    float v1 = fmaxf(acc[ca][nb][1] + bs.y, 0.f);
                    float v2 = fmaxf(acc[ca][nb][2] + bs.z, 0.f);
                    float v3 = fmaxf(acc[ca][nb][3] + bs.w, 0.f);
                    s[nb] += v0 * wo.x + v1 * wo.y + v2 * wo.z + v3 * wo.w;
                }
            }
#pragma unroll
            for (int nb = 0; nb < 4; ++nb) {
                s[nb] += __shfl_xor(s[nb], 16);
                s[nb] += __shfl_xor(s[nb], 32);
            }
            if (lg == 0) {
#pragma unroll
                for (int nb = 0; nb < 4; ++nb) part[w * 64 + nb * 16 + lr] = s[nb];
            }
        }
        bar_lds();

        if (tid < TM) {
            float v = part[tid] + part[64 + tid] + part[128 + tid] + part[192 + tid] + bo[e];
            bmax = fmaxf(bmax, v);
        }
    }

    if (tid < TM) out[row0 + tid] = bmax;
}

extern "C" void kernel_launch(void* const* d_in, const int* in_sizes, int n_in,
                              void* d_out, int out_size, void* d_ws, size_t ws_size,
                              hipStream_t stream) {
    const float* coords = (const float*)d_in[0];
    const float* W0 = (const float*)d_in[1];
    const float* b0 = (const float*)d_in[2];
    const float* W1 = (const float*)d_in[3];
    const float* b1 = (const float*)d_in[4];
    const float* W2 = (const float*)d_in[5];
    const float* b2 = (const float*)d_in[6];
    const float* Wo = (const float*)d_in[7];
    const float* bo = (const float*)d_in[8];
    float* out = (float*)d_out;

    char* ws = (char*)d_ws;
    unsigned short* W1b = (unsigned short*)(ws);            // 256 KB
    unsigned short* W2b = (unsigned short*)(ws + 262144);   // 256 KB
    unsigned short* W0p = (unsigned short*)(ws + 524288);   // 64 KB

    prep_kernel<<<dim3(256), dim3(256), 0, stream>>>(
        W0, W1, W2, (unsigned int*)W1b, (unsigned int*)W2b, (unsigned int*)W0p);

    moe_main<<<dim3(NPTS / TM), dim3(256), 0, stream>>>(
        coords, b0, b1, b2, Wo, bo, W0p, W1b, W2b, out);
}